// Round 1
// baseline (425.877 us; speedup 1.0000x reference)
//
#include <hip/hip_runtime.h>

#define NQ 22
#define DIMN (1u << NQ)

struct LinvArg  { unsigned r[NQ]; };
struct MeasArg  { unsigned xm[11]; unsigned zm[11]; };
struct Meas2Arg { unsigned xm[11]; unsigned zm[11]; int qn[11]; unsigned zrow[NQ]; };

// ---------------- prep: zero accumulators, compute cos/sin tables ----------------
// trig layout: trig[l*44 + b] = cos(theta[l][21-b]/2), trig[l*44 + 22 + b] = sin(...)
__global__ __launch_bounds__(256) void k_prep(const float* __restrict__ theta,
                                              float* __restrict__ acc,
                                              float* __restrict__ trig) {
    int t = threadIdx.x;
    acc[t] = 0.f;
    if (t < 2 * NQ) {
        int l = t / NQ, q = t % NQ, b = NQ - 1 - q;
        float h = 0.5f * theta[t];
        trig[l * 2 * NQ + b]      = cosf(h);
        trig[l * 2 * NQ + NQ + b] = sinf(h);
    }
}

// ---------------- P0: phi = RY-layer-1 product state evaluated at Linv*y ----------
__global__ __launch_bounds__(256) void k_init(float* __restrict__ phi,
                                              const float* __restrict__ trig,
                                              LinvArg A) {
    unsigned y = blockIdx.x * 256u + threadIdx.x;
    float cv[NQ], sv[NQ];
#pragma unroll
    for (int b = 0; b < NQ; ++b) { cv[b] = trig[b]; sv[b] = trig[NQ + b]; }
    float prod = 1.f;
#pragma unroll
    for (int b = 1; b < NQ; ++b) {
        unsigned tb = (unsigned)__popc(y & A.r[b]) & 1u;
        prod *= tb ? sv[b] : cv[b];
    }
    unsigned t0 = (unsigned)__popc(y & A.r[0]) & 1u;   // bit 0 = qubit 21
    phi[y]        = prod * (t0 ? sv[0] : cv[0]);       // logical |0>
    phi[DIMN + y] = prod * (t0 ? cv[0] : -sv[0]);      // logical |1>
}

// ---------------- RY layer 2 on 5 high bits [shift..shift+4], in registers -------
__global__ __launch_bounds__(256) void k_hi(float* __restrict__ phi,
                                            const float* __restrict__ trig,
                                            int shift) {
    unsigned tid = blockIdx.x * 256u + threadIdx.x;        // [0, 2^17)
    unsigned lowmask = (1u << shift) - 1u;
    unsigned base = (tid & lowmask) | ((tid >> shift) << (shift + 5));
    float c[5], s[5];
#pragma unroll
    for (int j = 0; j < 5; ++j) {
        c[j] = trig[2 * NQ + shift + j];
        s[j] = trig[3 * NQ + shift + j];
    }
    float v0[32], v1[32];
#pragma unroll
    for (int e = 0; e < 32; ++e) {
        unsigned a = base | ((unsigned)e << shift);
        v0[e] = phi[a];
        v1[e] = phi[DIMN + a];
    }
#pragma unroll
    for (int j = 0; j < 5; ++j) {
#pragma unroll
        for (int e = 0; e < 32; ++e) {
            if (!(e & (1 << j))) {
                int e1 = e | (1 << j);
                float a0 = v0[e], a1 = v0[e1];
                v0[e]  = c[j] * a0 - s[j] * a1;
                v0[e1] = s[j] * a0 + c[j] * a1;
                float b0 = v1[e], b1 = v1[e1];
                v1[e]  = c[j] * b0 - s[j] * b1;
                v1[e1] = s[j] * b0 + c[j] * b1;
            }
        }
    }
#pragma unroll
    for (int e = 0; e < 32; ++e) {
        unsigned a = base | ((unsigned)e << shift);
        phi[a] = v0[e];
        phi[DIMN + a] = v1[e];
    }
}

__device__ __forceinline__ void reduce_block(float* vals, int n, float* red,
                                             float* target, int t) {
    int lane = t & 63, w = t >> 6;
#pragma unroll
    for (int j = 0; j < 4; ++j) {
        if (j < n) {
            float v = vals[j];
            v += __shfl_down(v, 32); v += __shfl_down(v, 16); v += __shfl_down(v, 8);
            v += __shfl_down(v, 4);  v += __shfl_down(v, 2);  v += __shfl_down(v, 1);
            if (lane == 0) red[w * 4 + j] = v;
        }
    }
    __syncthreads();
    if (t < n) {
        float r = red[t] + red[4 + t] + red[8 + t] + red[12 + t];
        atomicAdd(&target[t], r);
    }
    __syncthreads();
}

// ------- RY layer 2 on bits 0..11 in LDS + measurements with xmask in low 12 bits --
__global__ __launch_bounds__(256) void k_low(float* __restrict__ phi,
                                             const float* __restrict__ trig,
                                             float* __restrict__ acc,
                                             MeasArg M) {
    __shared__ float A[4096];
    __shared__ float B[4096];
    __shared__ float red[16];
    int t = threadIdx.x;
    unsigned base = blockIdx.x * 4096u;
#pragma unroll
    for (int k = 0; k < 16; ++k) {
        A[t + 256 * k] = phi[base + t + 256 * k];
        B[t + 256 * k] = phi[DIMN + base + t + 256 * k];
    }
    __syncthreads();
    for (int g = 0; g < 12; ++g) {
        float c = trig[2 * NQ + g], s = trig[3 * NQ + g];
#pragma unroll
        for (int k = 0; k < 8; ++k) {
            unsigned p = (unsigned)t + 256u * k;            // pair index [0,2048)
            unsigned l0 = ((p >> g) << (g + 1)) | (p & ((1u << g) - 1u));
            unsigned l1 = l0 | (1u << g);
            float a0 = A[l0], a1 = A[l1];
            A[l0] = c * a0 - s * a1;
            A[l1] = s * a0 + c * a1;
            float b0 = B[l0], b1 = B[l1];
            B[l0] = c * b0 - s * b1;
            B[l1] = s * b0 + c * b1;
        }
        __syncthreads();
    }
#pragma unroll
    for (int k = 0; k < 16; ++k) {
        phi[base + t + 256 * k] = A[t + 256 * k];
        phi[DIMN + base + t + 256 * k] = B[t + 256 * k];
    }
    // measurements for qubits 10..20 (xmask within low 12 bits)
    for (int i = 0; i < 11; ++i) {
        unsigned m = M.xm[i], zm = M.zm[i];
        unsigned zb = (unsigned)__popc(base & zm) & 1u;
        float t00 = 0.f, t11 = 0.f, t01 = 0.f, u01 = 0.f;
#pragma unroll
        for (int k = 0; k < 16; ++k) {
            unsigned l = (unsigned)t + 256u * k;
            unsigned lx = l ^ m;
            float a0 = A[l], a1 = B[l];
            float b0 = A[lx], b1 = B[lx];
            t00 += a0 * b0;
            t11 += a1 * b1;
            float p = a0 * b1;
            t01 += p;
            unsigned sg = ((unsigned)__popc(lx & zm) + zb) & 1u;
            u01 += sg ? -p : p;
        }
        float vals[4] = { t00, t11, t01, u01 };
        reduce_block(vals, 4, red, &acc[4 * (10 + i)], t);
    }
}

// ------- measurements: high-bit xmasks (qubits 0..9, 21) + all 22 Z strings -------
__global__ __launch_bounds__(256) void k_meas2(const float* __restrict__ phi,
                                               float* __restrict__ acc,
                                               Meas2Arg M) {
    __shared__ float red[16];
    int t = threadIdx.x;
    unsigned gt = blockIdx.x * 256u + (unsigned)t;          // [0, 262144)
    int slice = blockIdx.y;
    const float4* p0 = (const float4*)phi;
    const float4* p1 = (const float4*)(phi + DIMN);
    if (slice < 11) {
        unsigned m = M.xm[slice], zm = M.zm[slice];
        unsigned mh4 = (m & ~3u) >> 2;
        int ml = (int)(m & 3u);
        float t00 = 0.f, t11 = 0.f, t01 = 0.f, u01 = 0.f;
#pragma unroll
        for (int it = 0; it < 4; ++it) {
            unsigned grp = gt + (unsigned)it * 262144u;     // group of 4 elements
            float4 a0 = p0[grp], a1 = p1[grp];
            unsigned pg = grp ^ mh4;
            float4 b0 = p0[pg], b1 = p1[pg];
            unsigned gbase = pg << 2;                       // high part of y^m
            float A0[4] = { a0.x, a0.y, a0.z, a0.w };
            float A1v[4] = { a1.x, a1.y, a1.z, a1.w };
            float B0[4] = { b0.x, b0.y, b0.z, b0.w };
            float B1[4] = { b1.x, b1.y, b1.z, b1.w };
#pragma unroll
            for (int i = 0; i < 4; ++i) {
                int ix = i ^ ml;
                float x0 = A0[i], x1 = A1v[i];
                float y0 = B0[ix], y1 = B1[ix];
                t00 += x0 * y0;
                t11 += x1 * y1;
                float p = x0 * y1;
                t01 += p;
                unsigned yx = gbase | (unsigned)ix;
                unsigned sg = (unsigned)__popc(yx & zm) & 1u;
                u01 += sg ? -p : p;
            }
        }
        float vals[4] = { t00, t11, t01, u01 };
        reduce_block(vals, 4, red, &acc[4 * M.qn[slice]], t);
    } else {
        float z00[NQ], z11[NQ], z01[NQ];
#pragma unroll
        for (int q = 0; q < NQ; ++q) { z00[q] = 0.f; z11[q] = 0.f; z01[q] = 0.f; }
#pragma unroll
        for (int it = 0; it < 4; ++it) {
            unsigned grp = gt + (unsigned)it * 262144u;
            float4 a0 = p0[grp], a1 = p1[grp];
            unsigned g = grp << 2;
            float A0[4] = { a0.x, a0.y, a0.z, a0.w };
            float A1v[4] = { a1.x, a1.y, a1.z, a1.w };
#pragma unroll
            for (int i = 0; i < 4; ++i) {
                float x0 = A0[i], x1 = A1v[i];
                float p00 = x0 * x0, p11 = x1 * x1, p01 = x0 * x1;
                unsigned y = g | (unsigned)i;
#pragma unroll
                for (int q = 0; q < NQ; ++q) {
                    unsigned sg = (unsigned)__popc(y & M.zrow[q]) & 1u;
                    z00[q] += sg ? -p00 : p00;
                    z11[q] += sg ? -p11 : p11;
                    z01[q] += sg ? -p01 : p01;
                }
            }
        }
#pragma unroll
        for (int q = 0; q < NQ; ++q) {
            float vals[3] = { z00[q], z11[q], z01[q] };
            reduce_block(vals, 3, red, &acc[4 * NQ + 3 * q], t);
        }
    }
}

// ---------------- finalize: combine 154 sums into the scalar loss ----------------
__global__ __launch_bounds__(64) void k_final(const float* __restrict__ acc,
                                              float* __restrict__ out) {
    int t = threadIdx.x;
    float v = 0.f;
    if (t < NQ) {
        float t00 = acc[4 * t], t11 = acc[4 * t + 1];
        float t01 = acc[4 * t + 2], u01 = acc[4 * t + 3];
        float d = t00 - t11;
        v = 0.5f * d * d + 2.f * t01 * t01 + 2.f * u01 * u01;   // X op + Y op
    } else if (t < 2 * NQ) {
        int q = t - NQ;
        float z0 = acc[4 * NQ + 3 * q], z1 = acc[4 * NQ + 3 * q + 1];
        float zz = acc[4 * NQ + 3 * q + 2];
        float d = z0 - z1;
        v = 0.5f * d * d + 2.f * zz * zz;                       // Z op
    }
    v += __shfl_down(v, 32); v += __shfl_down(v, 16); v += __shfl_down(v, 8);
    v += __shfl_down(v, 4);  v += __shfl_down(v, 2);  v += __shfl_down(v, 1);
    if (t == 0) out[0] = v;
}

extern "C" void kernel_launch(void* const* d_in, const int* in_sizes, int n_in,
                              void* d_out, int out_size, void* d_ws, size_t ws_size,
                              hipStream_t stream) {
    const float* theta = (const float*)d_in[0];
    float* out  = (float*)d_out;
    float* ws   = (float*)d_ws;
    float* phi  = ws;                          // 2 * DIMN floats (32 MB)
    float* acc  = ws + 2 * (size_t)DIMN;       // 256 floats
    float* trig = acc + 256;                   // 88 floats

    // Build L: basis map of one CNOT ring layer, |x> -> |Lx>, bit b of result =
    // parity(x & L[b]).  Qubit q lives at bit (21-q).
    unsigned L[NQ];
    for (int b = 0; b < NQ; ++b) L[b] = 1u << b;
    for (int q = 0; q < NQ; ++q) {
        int bc = NQ - 1 - q;
        int bt = NQ - 1 - ((q + 1) % NQ);
        L[bt] ^= L[bc];
    }
    // Invert over GF(2) (Gauss-Jordan): x_b = parity(y & Linv[b])
    unsigned mat[NQ], aug[NQ];
    for (int b = 0; b < NQ; ++b) { mat[b] = L[b]; aug[b] = 1u << b; }
    for (int col = 0; col < NQ; ++col) {
        int piv = col;
        while (!((mat[piv] >> col) & 1u)) ++piv;
        unsigned tm = mat[piv]; mat[piv] = mat[col]; mat[col] = tm;
        unsigned ta = aug[piv]; aug[piv] = aug[col]; aug[col] = ta;
        for (int r = 0; r < NQ; ++r)
            if (r != col && ((mat[r] >> col) & 1u)) { mat[r] ^= mat[col]; aug[r] ^= aug[col]; }
    }
    LinvArg la;
    for (int b = 0; b < NQ; ++b) la.r[b] = aug[b];

    // Conjugated Pauli masks: X_q -> X^(col 21-q of Linv); Z_q -> Z^(row 21-q of L)
    unsigned xmask[NQ], zmask[NQ];
    for (int j = 0; j < NQ; ++j) {
        int b = NQ - 1 - j;
        unsigned xm = 0;
        for (int r = 0; r < NQ; ++r)
            if ((aug[r] >> b) & 1u) xm |= 1u << r;
        xmask[j] = xm;          // analytically: adjacent-bit pairs; q=21 adds bit 0
        zmask[j] = L[b];
    }
    MeasArg ma;
    for (int i = 0; i < 11; ++i) { ma.xm[i] = xmask[10 + i]; ma.zm[i] = zmask[10 + i]; }
    Meas2Arg m2;
    for (int i = 0; i < 10; ++i) { m2.xm[i] = xmask[i]; m2.zm[i] = zmask[i]; m2.qn[i] = i; }
    m2.xm[10] = xmask[21]; m2.zm[10] = zmask[21]; m2.qn[10] = 21;
    for (int q = 0; q < NQ; ++q) m2.zrow[q] = zmask[q];

    k_prep<<<1, 256, 0, stream>>>(theta, acc, trig);
    k_init<<<DIMN / 256, 256, 0, stream>>>(phi, trig, la);
    k_hi<<<512, 256, 0, stream>>>(phi, trig, 12);
    k_hi<<<512, 256, 0, stream>>>(phi, trig, 17);
    k_low<<<1024, 256, 0, stream>>>(phi, trig, acc, ma);
    k_meas2<<<dim3(1024, 12), 256, 0, stream>>>(phi, acc, m2);
    k_final<<<1, 64, 0, stream>>>(acc, out);
}

// Round 2
// 298.302 us; speedup vs baseline: 1.4277x; 1.4277x over previous
//
#include <hip/hip_runtime.h>

#define NQ 22
#define DIMN (1u << NQ)

struct LinvArg  { unsigned r[NQ]; };
struct MeasArg  { unsigned xm[11]; unsigned zm[11]; };
struct MeasHArg { unsigned mh[11]; unsigned ml[11]; unsigned zm[11]; int qn[11]; };

// ---------------- prep: zero accumulators, compute cos/sin tables ----------------
// trig layout: trig[l*44 + b] = cos(theta[l][21-b]/2), trig[l*44 + 22 + b] = sin(...)
__global__ __launch_bounds__(256) void k_prep(const float* __restrict__ theta,
                                              float* __restrict__ acc,
                                              float* __restrict__ trig) {
    int t = threadIdx.x;
    acc[t] = 0.f;
    if (t < 2 * NQ) {
        int l = t / NQ, q = t % NQ, b = NQ - 1 - q;
        float h = 0.5f * theta[t];
        trig[l * 2 * NQ + b]      = cosf(h);
        trig[l * 2 * NQ + NQ + b] = sinf(h);
    }
}

// ---------------- P0: phi = RY-layer-1 product state evaluated at Linv*y ----------
__global__ __launch_bounds__(256) void k_init(float* __restrict__ phi,
                                              const float* __restrict__ trig,
                                              LinvArg A) {
    unsigned y = blockIdx.x * 256u + threadIdx.x;
    float cv[NQ], sv[NQ];
#pragma unroll
    for (int b = 0; b < NQ; ++b) { cv[b] = trig[b]; sv[b] = trig[NQ + b]; }
    float prod = 1.f;
#pragma unroll
    for (int b = 1; b < NQ; ++b) {
        unsigned tb = (unsigned)__popc(y & A.r[b]) & 1u;
        prod *= tb ? sv[b] : cv[b];
    }
    unsigned t0 = (unsigned)__popc(y & A.r[0]) & 1u;   // bit 0 = qubit 21
    phi[y]        = prod * (t0 ? sv[0] : cv[0]);       // logical |0>
    phi[DIMN + y] = prod * (t0 ? cv[0] : -sv[0]);      // logical |1>
}

// ---------------- RY layer 2 on 5 high bits [shift..shift+4], in registers -------
__global__ __launch_bounds__(256) void k_hi(float* __restrict__ phi,
                                            const float* __restrict__ trig,
                                            int shift) {
    unsigned tid = blockIdx.x * 256u + threadIdx.x;        // [0, 2^17)
    unsigned lowmask = (1u << shift) - 1u;
    unsigned base = (tid & lowmask) | ((tid >> shift) << (shift + 5));
    float c[5], s[5];
#pragma unroll
    for (int j = 0; j < 5; ++j) {
        c[j] = trig[2 * NQ + shift + j];
        s[j] = trig[3 * NQ + shift + j];
    }
    float v0[32], v1[32];
#pragma unroll
    for (int e = 0; e < 32; ++e) {
        unsigned a = base | ((unsigned)e << shift);
        v0[e] = phi[a];
        v1[e] = phi[DIMN + a];
    }
#pragma unroll
    for (int j = 0; j < 5; ++j) {
#pragma unroll
        for (int e = 0; e < 32; ++e) {
            if (!(e & (1 << j))) {
                int e1 = e | (1 << j);
                float a0 = v0[e], a1 = v0[e1];
                v0[e]  = c[j] * a0 - s[j] * a1;
                v0[e1] = s[j] * a0 + c[j] * a1;
                float b0 = v1[e], b1 = v1[e1];
                v1[e]  = c[j] * b0 - s[j] * b1;
                v1[e1] = s[j] * b0 + c[j] * b1;
            }
        }
    }
#pragma unroll
    for (int e = 0; e < 32; ++e) {
        unsigned a = base | ((unsigned)e << shift);
        phi[a] = v0[e];
        phi[DIMN + a] = v1[e];
    }
}

// block reduce for 256-thread blocks (4 waves)
__device__ __forceinline__ void reduce_block(float* vals, int n, float* red,
                                             float* target, int t) {
    int lane = t & 63, w = t >> 6;
#pragma unroll
    for (int j = 0; j < 4; ++j) {
        if (j < n) {
            float v = vals[j];
            v += __shfl_down(v, 32); v += __shfl_down(v, 16); v += __shfl_down(v, 8);
            v += __shfl_down(v, 4);  v += __shfl_down(v, 2);  v += __shfl_down(v, 1);
            if (lane == 0) red[w * 4 + j] = v;
        }
    }
    __syncthreads();
    if (t < n) {
        float r = red[t] + red[4 + t] + red[8 + t] + red[12 + t];
        atomicAdd(&target[t], r);
    }
    __syncthreads();
}

// block reduce for 512-thread blocks (8 waves)
__device__ __forceinline__ void reduce_block8(float* vals, int n, float* red,
                                              float* target, int t) {
    int lane = t & 63, w = t >> 6;
#pragma unroll
    for (int j = 0; j < 4; ++j) {
        if (j < n) {
            float v = vals[j];
            v += __shfl_down(v, 32); v += __shfl_down(v, 16); v += __shfl_down(v, 8);
            v += __shfl_down(v, 4);  v += __shfl_down(v, 2);  v += __shfl_down(v, 1);
            if (lane == 0) red[w * 4 + j] = v;
        }
    }
    __syncthreads();
    if (t < n) {
        float r = 0.f;
#pragma unroll
        for (int w2 = 0; w2 < 8; ++w2) r += red[w2 * 4 + t];
        atomicAdd(&target[t], r);
    }
    __syncthreads();
}

// ------- RY layer 2 on bits 0..11 in LDS + measurements with xmask in low 12 bits --
__global__ __launch_bounds__(256) void k_low(float* __restrict__ phi,
                                             const float* __restrict__ trig,
                                             float* __restrict__ acc,
                                             MeasArg M) {
    __shared__ float A[4096];
    __shared__ float B[4096];
    __shared__ float red[16];
    int t = threadIdx.x;
    unsigned base = blockIdx.x * 4096u;
#pragma unroll
    for (int k = 0; k < 16; ++k) {
        A[t + 256 * k] = phi[base + t + 256 * k];
        B[t + 256 * k] = phi[DIMN + base + t + 256 * k];
    }
    __syncthreads();
    for (int g = 0; g < 12; ++g) {
        float c = trig[2 * NQ + g], s = trig[3 * NQ + g];
#pragma unroll
        for (int k = 0; k < 8; ++k) {
            unsigned p = (unsigned)t + 256u * k;            // pair index [0,2048)
            unsigned l0 = ((p >> g) << (g + 1)) | (p & ((1u << g) - 1u));
            unsigned l1 = l0 | (1u << g);
            float a0 = A[l0], a1 = A[l1];
            A[l0] = c * a0 - s * a1;
            A[l1] = s * a0 + c * a1;
            float b0 = B[l0], b1 = B[l1];
            B[l0] = c * b0 - s * b1;
            B[l1] = s * b0 + c * b1;
        }
        __syncthreads();
    }
#pragma unroll
    for (int k = 0; k < 16; ++k) {
        phi[base + t + 256 * k] = A[t + 256 * k];
        phi[DIMN + base + t + 256 * k] = B[t + 256 * k];
    }
    // measurements for qubits 10..20 (xmask within low 12 bits)
    for (int i = 0; i < 11; ++i) {
        unsigned m = M.xm[i], zm = M.zm[i];
        unsigned zb = (unsigned)__popc(base & zm) & 1u;
        float t00 = 0.f, t11 = 0.f, t01 = 0.f, u01 = 0.f;
#pragma unroll
        for (int k = 0; k < 16; ++k) {
            unsigned l = (unsigned)t + 256u * k;
            unsigned lx = l ^ m;
            float a0 = A[l], a1 = B[l];
            float b0 = A[lx], b1 = B[lx];
            t00 += a0 * b0;
            t11 += a1 * b1;
            float p = a0 * b1;
            t01 += p;
            unsigned sg = ((unsigned)__popc(lx & zm) + zb) & 1u;
            u01 += sg ? -p : p;
        }
        float vals[4] = { t00, t11, t01, u01 };
        reduce_block(vals, 4, red, &acc[4 * (10 + i)], t);
    }
}

// ------- transposed-tile measurements: 11 high-bit X masks + all 22 Z strings ------
// Tile: all 2048 high-bit values (bits 11..21) x 4 consecutive low values, in LDS.
__global__ __launch_bounds__(512) void k_measH(const float* __restrict__ phi,
                                               float* __restrict__ acc,
                                               MeasHArg M) {
    __shared__ float4 Ald[2048];
    __shared__ float4 Bld[2048];
    __shared__ float red[32];
    int t = threadIdx.x;
    unsigned bi = blockIdx.x;
    // XCD-friendly l0 assignment: blocks sharing a 64B line land on one XCD
    unsigned l0 = (bi & 7u) * 256u + (bi >> 3) * 4u;   // multiple of 4 in [0,2048)
    unsigned c4 = l0 >> 2;
    const float4* p0 = (const float4*)phi;
    const float4* p1 = (const float4*)(phi + DIMN);

    // ---- load tile (strided gather) + Z-string accumulation in registers ----
    float z[NQ][3];
#pragma unroll
    for (int q = 0; q < NQ; ++q) { z[q][0] = 0.f; z[q][1] = 0.f; z[q][2] = 0.f; }
#pragma unroll
    for (int i = 0; i < 4; ++i) {
        unsigned h = (unsigned)t + 512u * i;
        float4 a = p0[h * 512u + c4];
        float4 b = p1[h * 512u + c4];
        Ald[h] = a; Bld[h] = b;
        float A0[4] = { a.x, a.y, a.z, a.w };
        float A1[4] = { b.x, b.y, b.z, b.w };
#pragma unroll
        for (int j = 0; j < 4; ++j) {
            unsigned y = (h << 11) | (l0 + (unsigned)j);
            unsigned W = y; W ^= W >> 1; W ^= W >> 2; W ^= W >> 4; W ^= W >> 8; W ^= W >> 16;
            float p00 = A0[j] * A0[j], p11 = A1[j] * A1[j], p01 = A0[j] * A1[j];
#pragma unroll
            for (int q = 0; q < NQ; ++q) {
                // zmask[q] is a suffix mask: sign = parity(y >> (21-q)); q=0 excludes bit 21
                unsigned sg = (q == 0) ? ((W ^ (W >> 21)) & 1u)
                                       : ((W >> (21 - q)) & 1u);
                float sf = sg ? -1.f : 1.f;
                z[q][0] += sf * p00;
                z[q][1] += sf * p11;
                z[q][2] += sf * p01;
            }
        }
    }
    __syncthreads();
    // reduce Z partials (frees the 66 accumulator registers)
#pragma unroll
    for (int q = 0; q < NQ; ++q) {
        float vals[3] = { z[q][0], z[q][1], z[q][2] };
        reduce_block8(vals, 3, red, &acc[4 * NQ + 3 * q], t);
    }

    // ---- 11 high-mask X/Y measurements, unordered-pair iteration in LDS ----
#pragma unroll
    for (int i = 0; i < 11; ++i) {
        unsigned mh = M.mh[i];              // mask on h bits (bits 11..21 -> 0..10)
        unsigned ml = M.ml[i];              // mask on low bits (0 or 1)
        unsigned zm = M.zm[i];
        unsigned zmh = zm >> 11;
        int hb = 31 - __clz((int)mh);       // top bit of mh
        float slp[4];
#pragma unroll
        for (int j = 0; j < 4; ++j) {
            unsigned lp = (unsigned)j ^ ml;
            slp[j] = ((unsigned)__popc((l0 + lp) & zm) & 1u) ? -1.f : 1.f;
        }
        float t00 = 0.f, t11 = 0.f, t01 = 0.f, u01 = 0.f;
#pragma unroll
        for (int it = 0; it < 2; ++it) {
            unsigned hp = (unsigned)t + 512u * it;          // [0,1024)
            unsigned h = ((hp >> hb) << (hb + 1)) | (hp & ((1u << hb) - 1u));
            unsigned hx = h ^ mh;
            float4 a0h = Ald[h],  a1h = Bld[h];
            float4 a0x = Ald[hx], a1x = Bld[hx];
            float4 pa0x = ml ? make_float4(a0x.y, a0x.x, a0x.w, a0x.z) : a0x;
            float4 pa1x = ml ? make_float4(a1x.y, a1x.x, a1x.w, a1x.z) : a1x;
            float4 pa1h = ml ? make_float4(a1h.y, a1h.x, a1h.w, a1h.z) : a1h;
            t00 += 2.f * (a0h.x * pa0x.x + a0h.y * pa0x.y + a0h.z * pa0x.z + a0h.w * pa0x.w);
            float4 pa1x_t = ml ? make_float4(a1x.y, a1x.x, a1x.w, a1x.z) : a1x; // for t11
            t11 += 2.f * (a1h.x * pa1x_t.x + a1h.y * pa1x_t.y + a1h.z * pa1x_t.z + a1h.w * pa1x_t.w);
            t01 += (a0h.x * pa1x.x + a0h.y * pa1x.y + a0h.z * pa1x.z + a0h.w * pa1x.w)
                 + (a0x.x * pa1h.x + a0x.y * pa1h.y + a0x.z * pa1h.z + a0x.w * pa1h.w);
            unsigned sh  = (unsigned)__popc(h & zmh) & 1u;
            unsigned shx = (unsigned)__popc(hx & zmh) & 1u;
            float e1 = slp[0] * a0h.x * pa1x.x + slp[1] * a0h.y * pa1x.y
                     + slp[2] * a0h.z * pa1x.z + slp[3] * a0h.w * pa1x.w;
            float e2 = slp[0] * a0x.x * pa1h.x + slp[1] * a0x.y * pa1h.y
                     + slp[2] * a0x.z * pa1h.z + slp[3] * a0x.w * pa1h.w;
            u01 += (shx ? -e1 : e1) + (sh ? -e2 : e2);
        }
        float vals[4] = { t00, t11, t01, u01 };
        reduce_block8(vals, 4, red, &acc[4 * M.qn[i]], t);
    }
}

// ---------------- finalize: combine 154 sums into the scalar loss ----------------
__global__ __launch_bounds__(64) void k_final(const float* __restrict__ acc,
                                              float* __restrict__ out) {
    int t = threadIdx.x;
    float v = 0.f;
    if (t < NQ) {
        float t00 = acc[4 * t], t11 = acc[4 * t + 1];
        float t01 = acc[4 * t + 2], u01 = acc[4 * t + 3];
        float d = t00 - t11;
        v = 0.5f * d * d + 2.f * t01 * t01 + 2.f * u01 * u01;   // X op + Y op
    } else if (t < 2 * NQ) {
        int q = t - NQ;
        float z0 = acc[4 * NQ + 3 * q], z1 = acc[4 * NQ + 3 * q + 1];
        float zz = acc[4 * NQ + 3 * q + 2];
        float d = z0 - z1;
        v = 0.5f * d * d + 2.f * zz * zz;                       // Z op
    }
    v += __shfl_down(v, 32); v += __shfl_down(v, 16); v += __shfl_down(v, 8);
    v += __shfl_down(v, 4);  v += __shfl_down(v, 2);  v += __shfl_down(v, 1);
    if (t == 0) out[0] = v;
}

extern "C" void kernel_launch(void* const* d_in, const int* in_sizes, int n_in,
                              void* d_out, int out_size, void* d_ws, size_t ws_size,
                              hipStream_t stream) {
    const float* theta = (const float*)d_in[0];
    float* out  = (float*)d_out;
    float* ws   = (float*)d_ws;
    float* phi  = ws;                          // 2 * DIMN floats (32 MB)
    float* acc  = ws + 2 * (size_t)DIMN;       // 256 floats
    float* trig = acc + 256;                   // 88 floats

    // Build L: basis map of one CNOT ring layer, |x> -> |Lx>, bit b of result =
    // parity(x & L[b]).  Qubit q lives at bit (21-q).
    unsigned L[NQ];
    for (int b = 0; b < NQ; ++b) L[b] = 1u << b;
    for (int q = 0; q < NQ; ++q) {
        int bc = NQ - 1 - q;
        int bt = NQ - 1 - ((q + 1) % NQ);
        L[bt] ^= L[bc];
    }
    // Invert over GF(2) (Gauss-Jordan): x_b = parity(y & Linv[b])
    unsigned mat[NQ], aug[NQ];
    for (int b = 0; b < NQ; ++b) { mat[b] = L[b]; aug[b] = 1u << b; }
    for (int col = 0; col < NQ; ++col) {
        int piv = col;
        while (!((mat[piv] >> col) & 1u)) ++piv;
        unsigned tm = mat[piv]; mat[piv] = mat[col]; mat[col] = tm;
        unsigned ta = aug[piv]; aug[piv] = aug[col]; aug[col] = ta;
        for (int r = 0; r < NQ; ++r)
            if (r != col && ((mat[r] >> col) & 1u)) { mat[r] ^= mat[col]; aug[r] ^= aug[col]; }
    }
    LinvArg la;
    for (int b = 0; b < NQ; ++b) la.r[b] = aug[b];

    // Conjugated Pauli masks: X_q -> X^(col 21-q of Linv); Z_q -> Z^(row 21-q of L)
    unsigned xmask[NQ], zmask[NQ];
    for (int j = 0; j < NQ; ++j) {
        int b = NQ - 1 - j;
        unsigned xm = 0;
        for (int r = 0; r < NQ; ++r)
            if ((aug[r] >> b) & 1u) xm |= 1u << r;
        xmask[j] = xm;          // qubits 0..9: bit-pairs {20-j,21-j}; qubit 21: {0,20,21}
        zmask[j] = L[b];        // suffix masks
    }
    MeasArg ma;
    for (int i = 0; i < 11; ++i) { ma.xm[i] = xmask[10 + i]; ma.zm[i] = zmask[10 + i]; }
    MeasHArg mh;
    for (int i = 0; i < 11; ++i) {
        int q = (i < 10) ? i : 21;
        mh.mh[i] = xmask[q] >> 11;
        mh.ml[i] = xmask[q] & 0x7FFu;
        mh.zm[i] = zmask[q];
        mh.qn[i] = q;
    }

    k_prep<<<1, 256, 0, stream>>>(theta, acc, trig);
    k_init<<<DIMN / 256, 256, 0, stream>>>(phi, trig, la);
    k_hi<<<512, 256, 0, stream>>>(phi, trig, 12);
    k_hi<<<512, 256, 0, stream>>>(phi, trig, 17);
    k_low<<<1024, 256, 0, stream>>>(phi, trig, acc, ma);
    k_measH<<<512, 512, 0, stream>>>(phi, acc, mh);
    k_final<<<1, 64, 0, stream>>>(acc, out);
}

// Round 3
// 217.678 us; speedup vs baseline: 1.9565x; 1.3704x over previous
//
#include <hip/hip_runtime.h>

#define NQ 22
#define DIMN (1u << NQ)

struct LinvArg  { unsigned r[NQ]; };
struct MeasLArg { unsigned xm[11]; unsigned zm[11]; int gbit[11]; };
struct MeasXArg { unsigned xm[11]; unsigned zm[11]; int gbit[11]; int qn[11]; };

// ---------------- prep: zero accumulators, compute cos/sin tables ----------------
// trig layout: trig[l*44 + b] = cos(theta[l][21-b]/2), trig[l*44 + 22 + b] = sin(...)
__global__ __launch_bounds__(256) void k_prep(const float* __restrict__ theta,
                                              float* __restrict__ acc,
                                              float* __restrict__ trig) {
    int t = threadIdx.x;
    acc[t] = 0.f;
    if (t < 2 * NQ) {
        int l = t / NQ, q = t % NQ, b = NQ - 1 - q;
        float h = 0.5f * theta[t];
        trig[l * 2 * NQ + b]      = cosf(h);
        trig[l * 2 * NQ + NQ + b] = sinf(h);
    }
}

// ---------------- P0: phi = RY-layer-1 product state evaluated at Linv*y ----------
__global__ __launch_bounds__(256) void k_init(float* __restrict__ phi,
                                              const float* __restrict__ trig,
                                              LinvArg A) {
    unsigned y = blockIdx.x * 256u + threadIdx.x;
    float cv[NQ], sv[NQ];
#pragma unroll
    for (int b = 0; b < NQ; ++b) { cv[b] = trig[b]; sv[b] = trig[NQ + b]; }
    float prod = 1.f;
#pragma unroll
    for (int b = 1; b < NQ; ++b) {
        unsigned tb = (unsigned)__popc(y & A.r[b]) & 1u;
        prod *= tb ? sv[b] : cv[b];
    }
    unsigned t0 = (unsigned)__popc(y & A.r[0]) & 1u;   // bit 0 = qubit 21
    phi[y]        = prod * (t0 ? sv[0] : cv[0]);       // logical |0>
    phi[DIMN + y] = prod * (t0 ? cv[0] : -sv[0]);      // logical |1>
}

// ---------------- RY layer 2 on 5 high bits [shift..shift+4], in registers -------
__global__ __launch_bounds__(256) void k_hi(float* __restrict__ phi,
                                            const float* __restrict__ trig,
                                            int shift) {
    unsigned tid = blockIdx.x * 256u + threadIdx.x;        // [0, 2^17)
    unsigned lowmask = (1u << shift) - 1u;
    unsigned base = (tid & lowmask) | ((tid >> shift) << (shift + 5));
    float c[5], s[5];
#pragma unroll
    for (int j = 0; j < 5; ++j) {
        c[j] = trig[2 * NQ + shift + j];
        s[j] = trig[3 * NQ + shift + j];
    }
    float v0[32], v1[32];
#pragma unroll
    for (int e = 0; e < 32; ++e) {
        unsigned a = base | ((unsigned)e << shift);
        v0[e] = phi[a];
        v1[e] = phi[DIMN + a];
    }
#pragma unroll
    for (int j = 0; j < 5; ++j) {
#pragma unroll
        for (int e = 0; e < 32; ++e) {
            if (!(e & (1 << j))) {
                int e1 = e | (1 << j);
                float a0 = v0[e], a1 = v0[e1];
                v0[e]  = c[j] * a0 - s[j] * a1;
                v0[e1] = s[j] * a0 + c[j] * a1;
                float b0 = v1[e], b1 = v1[e1];
                v1[e]  = c[j] * b0 - s[j] * b1;
                v1[e1] = s[j] * b0 + c[j] * b1;
            }
        }
    }
#pragma unroll
    for (int e = 0; e < 32; ++e) {
        unsigned a = base | ((unsigned)e << shift);
        phi[a] = v0[e];
        phi[DIMN + a] = v1[e];
    }
}

__device__ __forceinline__ float wave_sum(float v) {
    v += __shfl_down(v, 32); v += __shfl_down(v, 16); v += __shfl_down(v, 8);
    v += __shfl_down(v, 4);  v += __shfl_down(v, 2);  v += __shfl_down(v, 1);
    return v;
}
__device__ __forceinline__ float fflip(float v, unsigned sbit31) {
    return __int_as_float(__float_as_int(v) ^ (int)sbit31);
}
// LDS bank swizzle: scalar addr i -> i ^ (((i>>8)&3)<<2); float4 idx g -> g ^ ((g>>6)&3)
__device__ __forceinline__ unsigned ph1(unsigned i) { return i ^ (((i >> 8) & 3u) << 2); }
__device__ __forceinline__ unsigned ph4(unsigned g) { return g ^ ((g >> 6) & 3u); }

// ------- RY layer 2 on bits 0..11 (register-staged) + low-mask measurements --------
__global__ __launch_bounds__(256) void k_low(float* __restrict__ phi,
                                             const float* __restrict__ trig,
                                             float* __restrict__ acc,
                                             MeasLArg M) {
    __shared__ float As[4096];
    __shared__ float Bs[4096];
    __shared__ float red[4 * 44];
    float4* As4 = (float4*)As;
    float4* Bs4 = (float4*)Bs;
    int t = threadIdx.x;
    unsigned base = blockIdx.x * 4096u;
    float a[16], b[16];

    // ---- phase 0: global load (16 consecutive elems/thread), gates bits 0..3 ----
    {
        const float4* g0 = (const float4*)(phi + base);
        const float4* g1 = (const float4*)(phi + DIMN + base);
#pragma unroll
        for (int k = 0; k < 4; ++k) {
            float4 va = g0[4 * t + k];
            a[4 * k] = va.x; a[4 * k + 1] = va.y; a[4 * k + 2] = va.z; a[4 * k + 3] = va.w;
            float4 vb = g1[4 * t + k];
            b[4 * k] = vb.x; b[4 * k + 1] = vb.y; b[4 * k + 2] = vb.z; b[4 * k + 3] = vb.w;
        }
#pragma unroll
        for (int g = 0; g < 4; ++g) {
            float c = trig[2 * NQ + g], s = trig[3 * NQ + g];
#pragma unroll
            for (int e = 0; e < 16; ++e) {
                if (!(e & (1 << g))) {
                    int e1 = e | (1 << g);
                    float x0 = a[e], x1 = a[e1];
                    a[e] = c * x0 - s * x1; a[e1] = s * x0 + c * x1;
                    float y0 = b[e], y1 = b[e1];
                    b[e] = c * y0 - s * y1; b[e1] = s * y0 + c * y1;
                }
            }
        }
        unsigned sw = (unsigned)(t >> 4) & 3u;
#pragma unroll
        for (int k = 0; k < 4; ++k) {
            unsigned f = ((unsigned)(4 * t + k)) ^ sw;
            As4[f] = make_float4(a[4 * k], a[4 * k + 1], a[4 * k + 2], a[4 * k + 3]);
            Bs4[f] = make_float4(b[4 * k], b[4 * k + 1], b[4 * k + 2], b[4 * k + 3]);
        }
    }
    __syncthreads();

    // ---- phase 1: exchange to bits 4..7 ownership, gates bits 4..7 ----
    {
        unsigned lo = (unsigned)t & 15u, hi = (unsigned)t >> 4;
        unsigned swz = (hi & 3u) << 2;
#pragma unroll
        for (int j = 0; j < 16; ++j) {
            unsigned i = lo | ((unsigned)j << 4) | (hi << 8);
            a[j] = As[i ^ swz];
            b[j] = Bs[i ^ swz];
        }
#pragma unroll
        for (int g = 0; g < 4; ++g) {
            float c = trig[2 * NQ + 4 + g], s = trig[3 * NQ + 4 + g];
#pragma unroll
            for (int e = 0; e < 16; ++e) {
                if (!(e & (1 << g))) {
                    int e1 = e | (1 << g);
                    float x0 = a[e], x1 = a[e1];
                    a[e] = c * x0 - s * x1; a[e1] = s * x0 + c * x1;
                    float y0 = b[e], y1 = b[e1];
                    b[e] = c * y0 - s * y1; b[e1] = s * y0 + c * y1;
                }
            }
        }
#pragma unroll
        for (int j = 0; j < 16; ++j) {
            unsigned i = lo | ((unsigned)j << 4) | (hi << 8);
            As[i ^ swz] = a[j];
            Bs[i ^ swz] = b[j];
        }
    }
    __syncthreads();

    // ---- phase 2: exchange to bits 8..11 ownership, gates bits 8..11, write out ----
    {
#pragma unroll
        for (int j = 0; j < 16; ++j) {
            unsigned i = (unsigned)t | ((unsigned)j << 8);
            unsigned p = i ^ (((unsigned)j & 3u) << 2);
            a[j] = As[p];
            b[j] = Bs[p];
        }
#pragma unroll
        for (int g = 0; g < 4; ++g) {
            float c = trig[2 * NQ + 8 + g], s = trig[3 * NQ + 8 + g];
#pragma unroll
            for (int e = 0; e < 16; ++e) {
                if (!(e & (1 << g))) {
                    int e1 = e | (1 << g);
                    float x0 = a[e], x1 = a[e1];
                    a[e] = c * x0 - s * x1; a[e1] = s * x0 + c * x1;
                    float y0 = b[e], y1 = b[e1];
                    b[e] = c * y0 - s * y1; b[e1] = s * y0 + c * y1;
                }
            }
        }
#pragma unroll
        for (int j = 0; j < 16; ++j) {
            unsigned i = (unsigned)t | ((unsigned)j << 8);
            phi[base + i] = a[j];
            phi[DIMN + base + i] = b[j];
            unsigned p = i ^ (((unsigned)j & 3u) << 2);
            As[p] = a[j];
            Bs[p] = b[j];
        }
    }
    __syncthreads();

    // ---- measurements q10..20 (masks within bits 0..11), vectorized from LDS ----
    int lane = t & 63, w = t >> 6;
    for (int i = 0; i < 11; ++i) {
        unsigned m = M.xm[i], zm = M.zm[i];
        unsigned zb = (unsigned)__popc(base & zm) & 1u;
        float t00 = 0.f, t11 = 0.f, t01 = 0.f, u01 = 0.f;
        if (i < 10) {
            // halved unordered-pair iteration over 512 group-pairs
            int gb = M.gbit[i];
            unsigned mg4 = m >> 2;
            unsigned swap2 = m & 3u;            // 0 or 2
#pragma unroll
            for (int r = 0; r < 2; ++r) {
                unsigned gc = (unsigned)t + 256u * r;
                unsigned g = ((gc >> gb) << (gb + 1)) | (gc & ((1u << gb) - 1u));
                unsigned gx = g ^ mg4;
                float4 a0 = As4[ph4(g)],  a1 = Bs4[ph4(g)];
                float4 b0 = As4[ph4(gx)], b1 = Bs4[ph4(gx)];
                if (swap2) {
                    b0 = make_float4(b0.z, b0.w, b0.x, b0.y);
                    b1 = make_float4(b1.z, b1.w, b1.x, b1.y);
                }
                unsigned szg = ((unsigned)__popc((g << 2) & zm) + zb) & 1u;
                unsigned szx = ((unsigned)__popc((gx << 2) & zm) + zb) & 1u;
                unsigned fg = szg << 31, fx = szx << 31;
                const float* A0 = &a0.x; const float* A1 = &a1.x;
                const float* B0 = &b0.x; const float* B1 = &b1.x;
#pragma unroll
                for (int j = 0; j < 4; ++j) {
                    t00 += A0[j] * B0[j];
                    t11 += A1[j] * B1[j];
                    float p = A0[j] * B1[j], r2 = B0[j] * A1[j];
                    t01 += p + r2;
                    u01 += fflip(p, fx) + fflip(r2, fg);
                }
            }
            t00 *= 2.f; t11 *= 2.f;
        } else {
            // q20: m = 3, partner within float4; full directed iteration
#pragma unroll
            for (int k = 0; k < 4; ++k) {
                unsigned g = (unsigned)t + 256u * k;
                float4 a0 = As4[ph4(g)], a1 = Bs4[ph4(g)];
                unsigned szg = ((unsigned)__popc((g << 2) & zm) + zb) & 1u;
                const float* A0 = &a0.x; const float* A1 = &a1.x;
#pragma unroll
                for (int j = 0; j < 4; ++j) {
                    int jx = j ^ 3;
                    float p = A0[j] * A0[jx];
                    float q2 = A1[j] * A1[jx];
                    float cr = A0[j] * A1[jx];
                    t00 += p; t11 += q2; t01 += cr;
                    unsigned sj = ((unsigned)(jx >> 1) & 1u) ^ szg;   // zm&3 == 2
                    u01 += fflip(cr, sj << 31);
                }
            }
        }
        float vals[4] = { t00, t11, t01, u01 };
#pragma unroll
        for (int j = 0; j < 4; ++j) {
            float v = wave_sum(vals[j]);
            if (lane == 0) red[w * 44 + 4 * i + j] = v;
        }
    }
    __syncthreads();
    if (t < 44) {
        float r = red[t] + red[44 + t] + red[88 + t] + red[132 + t];
        atomicAdd(&acc[40 + t], r);
    }
}

// ------- coalesced X/Y measurements for high masks (q0..9, q21), grid (256,11) ------
__global__ __launch_bounds__(256) void k_measX(const float* __restrict__ phi,
                                               float* __restrict__ acc,
                                               MeasXArg M) {
    __shared__ float red[16];
    int t = threadIdx.x;
    int slice = blockIdx.y;
    unsigned m = M.xm[slice], zm = M.zm[slice];
    int gb = M.gbit[slice];
    unsigned mg4 = m >> 2;
    unsigned ml2 = m & 3u;                      // 0 or 1
    unsigned zl = zm & 3u;
    // per-j sign patterns (bit31 masks)
    unsigned pg31[4], px31[4];
#pragma unroll
    for (int j = 0; j < 4; ++j) {
        pg31[j] = (((unsigned)__popc((unsigned)j & zl) & 1u) << 31);
        px31[j] = (((unsigned)__popc(((unsigned)j ^ ml2) & zl) & 1u) << 31);
    }
    unsigned tid = blockIdx.x * 256u + (unsigned)t;   // [0, 65536)
    const float4* p0 = (const float4*)phi;
    const float4* p1 = (const float4*)(phi + DIMN);
    float t00 = 0.f, t11 = 0.f, t01 = 0.f, u01 = 0.f;
#pragma unroll
    for (int it = 0; it < 8; ++it) {
        unsigned gc = tid + (unsigned)it * 65536u;    // [0, 2^19)
        unsigned g = ((gc >> gb) << (gb + 1)) | (gc & ((1u << gb) - 1u));
        unsigned gx = g ^ mg4;
        float4 a0 = p0[g], a1 = p1[g];
        float4 b0 = p0[gx], b1 = p1[gx];
        if (ml2) {
            b0 = make_float4(b0.y, b0.x, b0.w, b0.z);
            b1 = make_float4(b1.y, b1.x, b1.w, b1.z);
        }
        unsigned fg = (((unsigned)__popc((g << 2) & zm) & 1u) << 31);
        unsigned fx = (((unsigned)__popc((gx << 2) & zm) & 1u) << 31);
        const float* A0 = &a0.x; const float* A1 = &a1.x;
        const float* B0 = &b0.x; const float* B1 = &b1.x;
#pragma unroll
        for (int j = 0; j < 4; ++j) {
            t00 += A0[j] * B0[j];
            t11 += A1[j] * B1[j];
            float p = A0[j] * B1[j], r = B0[j] * A1[j];
            t01 += p + r;
            u01 += fflip(p, fx ^ px31[j]) + fflip(r, fg ^ pg31[j]);
        }
    }
    t00 *= 2.f; t11 *= 2.f;
    int lane = t & 63, w = t >> 6;
    float vals[4] = { t00, t11, t01, u01 };
#pragma unroll
    for (int j = 0; j < 4; ++j) {
        float v = wave_sum(vals[j]);
        if (lane == 0) red[w * 4 + j] = v;
    }
    __syncthreads();
    if (t < 4) {
        float r = red[t] + red[4 + t] + red[8 + t] + red[12 + t];
        atomicAdd(&acc[4 * M.qn[slice] + t], r);
    }
}

// ------- coalesced Z-string measurements (all 22 qubits), suffix-parity signs ------
__global__ __launch_bounds__(256) void k_measZ(const float* __restrict__ phi,
                                               float* __restrict__ acc) {
    __shared__ float red[4 * 66];
    int t = threadIdx.x;
    unsigned tid = blockIdx.x * 256u + (unsigned)t;   // [0, 262144)
    const float4* p0 = (const float4*)phi;
    const float4* p1 = (const float4*)(phi + DIMN);
    float z[66];
#pragma unroll
    for (int k = 0; k < 66; ++k) z[k] = 0.f;
#pragma unroll
    for (int c = 0; c < 4; ++c) {
        unsigned g = tid + (unsigned)c * 262144u;     // float4 group
        float4 a = p0[g], b = p1[g];
        unsigned yb = g << 2;
        unsigned W = yb; W ^= W >> 1; W ^= W >> 2; W ^= W >> 4; W ^= W >> 8; W ^= W >> 16;
        const float* A = &a.x; const float* B = &b.x;
        float S[3], C1[3], C2[3];
        {
            float p0v[4], p1v[4], pc[4];
#pragma unroll
            for (int j = 0; j < 4; ++j) {
                p0v[j] = A[j] * A[j]; p1v[j] = B[j] * B[j]; pc[j] = A[j] * B[j];
            }
            S[0]  = p0v[0] + p0v[1] + p0v[2] + p0v[3];
            C1[0] = p0v[0] - p0v[1] - p0v[2] + p0v[3];
            C2[0] = p0v[0] + p0v[1] - p0v[2] - p0v[3];
            S[1]  = p1v[0] + p1v[1] + p1v[2] + p1v[3];
            C1[1] = p1v[0] - p1v[1] - p1v[2] + p1v[3];
            C2[1] = p1v[0] + p1v[1] - p1v[2] - p1v[3];
            S[2]  = pc[0] + pc[1] + pc[2] + pc[3];
            C1[2] = pc[0] - pc[1] - pc[2] + pc[3];
            C2[2] = pc[0] + pc[1] - pc[2] - pc[3];
        }
#pragma unroll
        for (int q = 0; q < NQ; ++q) {
            unsigned sb;
            const float* V;
            if (q == 0)       { sb = (W ^ (W >> 21)) & 1u; V = C1; }
            else if (q == 20) { sb = (W >> 1) & 1u;        V = C2; }
            else if (q == 21) { sb = W & 1u;               V = C1; }
            else              { sb = (W >> (21 - q)) & 1u; V = S;  }
            unsigned fm = sb << 31;
            z[3 * q]     += fflip(V[0], fm);
            z[3 * q + 1] += fflip(V[1], fm);
            z[3 * q + 2] += fflip(V[2], fm);
        }
    }
    int lane = t & 63, w = t >> 6;
#pragma unroll
    for (int k = 0; k < 66; ++k) {
        float v = wave_sum(z[k]);
        if (lane == 0) red[w * 66 + k] = v;
    }
    __syncthreads();
    if (t < 66) {
        float r = red[t] + red[66 + t] + red[132 + t] + red[198 + t];
        atomicAdd(&acc[4 * NQ + t], r);
    }
}

// ---------------- finalize: combine 154 sums into the scalar loss ----------------
__global__ __launch_bounds__(64) void k_final(const float* __restrict__ acc,
                                              float* __restrict__ out) {
    int t = threadIdx.x;
    float v = 0.f;
    if (t < NQ) {
        float t00 = acc[4 * t], t11 = acc[4 * t + 1];
        float t01 = acc[4 * t + 2], u01 = acc[4 * t + 3];
        float d = t00 - t11;
        v = 0.5f * d * d + 2.f * t01 * t01 + 2.f * u01 * u01;   // X op + Y op
    } else if (t < 2 * NQ) {
        int q = t - NQ;
        float z0 = acc[4 * NQ + 3 * q], z1 = acc[4 * NQ + 3 * q + 1];
        float zz = acc[4 * NQ + 3 * q + 2];
        float d = z0 - z1;
        v = 0.5f * d * d + 2.f * zz * zz;                       // Z op
    }
    v += __shfl_down(v, 32); v += __shfl_down(v, 16); v += __shfl_down(v, 8);
    v += __shfl_down(v, 4);  v += __shfl_down(v, 2);  v += __shfl_down(v, 1);
    if (t == 0) out[0] = v;
}

extern "C" void kernel_launch(void* const* d_in, const int* in_sizes, int n_in,
                              void* d_out, int out_size, void* d_ws, size_t ws_size,
                              hipStream_t stream) {
    const float* theta = (const float*)d_in[0];
    float* out  = (float*)d_out;
    float* ws   = (float*)d_ws;
    float* phi  = ws;                          // 2 * DIMN floats (32 MB)
    float* acc  = ws + 2 * (size_t)DIMN;       // 256 floats
    float* trig = acc + 256;                   // 88 floats

    // Build L: basis map of one CNOT ring layer, |x> -> |Lx>, bit b of result =
    // parity(x & L[b]).  Qubit q lives at bit (21-q).
    unsigned L[NQ];
    for (int b = 0; b < NQ; ++b) L[b] = 1u << b;
    for (int q = 0; q < NQ; ++q) {
        int bc = NQ - 1 - q;
        int bt = NQ - 1 - ((q + 1) % NQ);
        L[bt] ^= L[bc];
    }
    // Invert over GF(2) (Gauss-Jordan): x_b = parity(y & Linv[b])
    unsigned mat[NQ], aug[NQ];
    for (int b = 0; b < NQ; ++b) { mat[b] = L[b]; aug[b] = 1u << b; }
    for (int col = 0; col < NQ; ++col) {
        int piv = col;
        while (!((mat[piv] >> col) & 1u)) ++piv;
        unsigned tm = mat[piv]; mat[piv] = mat[col]; mat[col] = tm;
        unsigned ta = aug[piv]; aug[piv] = aug[col]; aug[col] = ta;
        for (int r = 0; r < NQ; ++r)
            if (r != col && ((mat[r] >> col) & 1u)) { mat[r] ^= mat[col]; aug[r] ^= aug[col]; }
    }
    LinvArg la;
    for (int b = 0; b < NQ; ++b) la.r[b] = aug[b];

    // Conjugated Pauli masks: X_q -> X^(col 21-q of Linv); Z_q -> Z^(row 21-q of L)
    unsigned xmask[NQ], zmask[NQ];
    for (int j = 0; j < NQ; ++j) {
        int b = NQ - 1 - j;
        unsigned xm = 0;
        for (int r = 0; r < NQ; ++r)
            if ((aug[r] >> b) & 1u) xm |= 1u << r;
        xmask[j] = xm;          // q0..9: bit-pairs {21-j,20-j}; q10..20: low pairs; q21: {0,20,21}
        zmask[j] = L[b];        // suffix masks
    }
    auto topbit = [](unsigned v) { int b = 0; while (v >> (b + 1)) ++b; return b; };

    MeasLArg ml;
    for (int i = 0; i < 11; ++i) {
        int q = 10 + i;
        ml.xm[i] = xmask[q]; ml.zm[i] = zmask[q];
        ml.gbit[i] = topbit(xmask[q]) - 2;     // q10..19 (q20 special-cased)
    }
    MeasXArg mx;
    for (int i = 0; i < 11; ++i) {
        int q = (i < 10) ? i : 21;
        mx.xm[i] = xmask[q]; mx.zm[i] = zmask[q];
        mx.gbit[i] = topbit(xmask[q]) - 2;
        mx.qn[i] = q;
    }

    k_prep<<<1, 256, 0, stream>>>(theta, acc, trig);
    k_init<<<DIMN / 256, 256, 0, stream>>>(phi, trig, la);
    k_hi<<<512, 256, 0, stream>>>(phi, trig, 12);
    k_hi<<<512, 256, 0, stream>>>(phi, trig, 17);
    k_low<<<1024, 256, 0, stream>>>(phi, trig, acc, ml);
    k_measX<<<dim3(256, 11), 256, 0, stream>>>(phi, acc, mx);
    k_measZ<<<1024, 256, 0, stream>>>(phi, acc);
    k_final<<<1, 64, 0, stream>>>(acc, out);
}